// Round 2
// baseline (12424.013 us; speedup 1.0000x reference)
//
#include <hip/hip_runtime.h>
#include <hip/hip_bf16.h>

typedef __hip_bfloat16 bf16;
typedef __attribute__((ext_vector_type(8))) short bf16x8;
typedef __attribute__((ext_vector_type(4))) float f32x4;

#define SCOPE_AGENT __HIP_MEMORY_SCOPE_AGENT

// bf16 NaN pattern x4 — tanh output is always finite, so this value can never
// be produced by the RNN epilogue. Used as "not yet written" sentinel in z.
#define SENT8 0x7FC07FC07FC07FC0ULL

// ---------------------------------------------------------------- prep
__global__ void prep_k(const float* __restrict__ b_ih, const float* __restrict__ b_hh,
                       float* __restrict__ bias_sum, unsigned* __restrict__ cnt) {
    int i = blockIdx.x * 256 + threadIdx.x;
    if (i < 512)  bias_sum[i] = b_ih[i] + b_hh[i];
    if (i < 2048) cnt[i] = 0u;
}

__global__ void f2b_k(const float* __restrict__ in, bf16* __restrict__ out, long n) {
    long i = (long)blockIdx.x * blockDim.x + threadIdx.x;
    long stride = (long)gridDim.x * blockDim.x;
    for (; i < n; i += stride) out[i] = __float2bfloat16(in[i]);
}

// fill z with the sentinel pattern (value-based dataflow sync in rnn_k)
__global__ void fill_k(unsigned long long* __restrict__ p, long n) {
    long i = (long)blockIdx.x * blockDim.x + threadIdx.x;
    long stride = (long)gridDim.x * blockDim.x;
    for (; i < n; i += stride) p[i] = SENT8;
}

// ---------------------------------------------------------------- generic bf16 MFMA GEMM
// C[m,n] = sum_k A(m,k)*B(k,n)  (+ Cin, + bias[n])
// A(m,k) = A[(gather?gidx[m]:m)*lda + k]          (row-major over k)
// BT=true : B(k,n) = B[n*ldb + k]  (B stored [N][K], i.e. B^T row-major)
// BT=false: B(k,n) = B[k*ldb + n]  (B stored [K][N] row-major)
template<bool BT, bool OUT_BF16, bool ACCUM, bool BIAS, bool GATHER>
__global__ __launch_bounds__(256) void gemm_k(
    const bf16* __restrict__ A, long lda, long a_bs,
    const int* __restrict__ gidx,
    const bf16* __restrict__ B, long ldb, long b_bs,
    const float* __restrict__ bias,
    const float* __restrict__ Cin, long ldcin,
    void* __restrict__ Cout, long ldc, long c_bs,
    int M, int N, int K)
{
    constexpr int BM = 128, BN = 128, BK = 32, PAD = 8;
    __shared__ bf16 As[BM][BK + PAD];   // [m][k]
    __shared__ bf16 Bs[BN][BK + PAD];   // [n][k]

    const int tid  = threadIdx.x;
    const int m0   = blockIdx.y * BM, n0 = blockIdx.x * BN;
    const long bat = blockIdx.z;
    const bf16* Ab = A + bat * a_bs;
    const bf16* Bb = B + bat * b_bs;
    const int wave = tid >> 6, lane = tid & 63;
    const int wm = (wave >> 1) * 64, wn = (wave & 1) * 64;
    const int lr = lane >> 4, lc = lane & 15;

    f32x4 acc[4][4] = {};

    for (int k0 = 0; k0 < K; k0 += BK) {
        // stage A tile: 128x32 bf16, 16B chunks
#pragma unroll
        for (int it = 0; it < 2; it++) {
            int c = tid + it * 256;
            int m = c >> 2, kc = (c & 3) * 8;
            long arow;
            if (GATHER) arow = (long)gidx[m0 + m];
            else        arow = (long)(m0 + m);
            *(uint4*)&As[m][kc] = *(const uint4*)(Ab + arow * lda + (k0 + kc));
        }
        if (BT) {
#pragma unroll
            for (int it = 0; it < 2; it++) {
                int c = tid + it * 256;
                int n = c >> 2, kc = (c & 3) * 8;
                int gn = n0 + n; if (gn >= N) gn = N - 1;   // clamp (K6: N=10000)
                *(uint4*)&Bs[n][kc] = *(const uint4*)(Bb + (long)gn * ldb + (k0 + kc));
            }
        } else {
            // B row-major [K][N]: read 8 along n, transpose into Bs
#pragma unroll
            for (int it = 0; it < 2; it++) {
                int c = tid + it * 256;
                int k = c >> 4, nc = (c & 15) * 8;
                union { uint4 u; bf16 h[8]; } uu;
                uu.u = *(const uint4*)(Bb + (long)(k0 + k) * ldb + (n0 + nc));
#pragma unroll
                for (int j = 0; j < 8; j++) Bs[nc + j][k] = uu.h[j];
            }
        }
        __syncthreads();

        bf16x8 af[4], bfr[4];
#pragma unroll
        for (int t = 0; t < 4; t++) {
            af[t]  = *(const bf16x8*)&As[wm + t * 16 + lc][lr * 8];
            bfr[t] = *(const bf16x8*)&Bs[wn + t * 16 + lc][lr * 8];
        }
#pragma unroll
        for (int mt = 0; mt < 4; mt++)
#pragma unroll
            for (int nt = 0; nt < 4; nt++)
                acc[mt][nt] = __builtin_amdgcn_mfma_f32_16x16x32_bf16(af[mt], bfr[nt], acc[mt][nt], 0, 0, 0);
        __syncthreads();
    }

    const long cb = bat * c_bs;
#pragma unroll
    for (int mt = 0; mt < 4; mt++)
#pragma unroll
        for (int nt = 0; nt < 4; nt++)
#pragma unroll
            for (int i = 0; i < 4; i++) {
                int r  = m0 + wm + mt * 16 + lr * 4 + i;   // row = quad*4+reg (m89)
                int cc = n0 + wn + nt * 16 + lc;           // col = lane&15
                if (r < M && cc < N) {
                    float v = acc[mt][nt][i];
                    if (ACCUM) v += Cin[(long)r * ldcin + cc];
                    if (BIAS)  v += bias[cc];
                    if (OUT_BF16) ((bf16*)Cout)[cb + (long)r * ldc + cc] = __float2bfloat16(v);
                    else          ((float*)Cout)[cb + (long)r * ldc + cc] = v;
                }
            }
}

// fast tanh: 1 - 2/(e^{2x}+1). Saturates exactly to +-1 (e^{2x}=inf -> 1;
// e^{2x}=0 -> -1). Error ~1e-6 relative, far below bf16 rounding.
__device__ __forceinline__ float fast_tanh(float x) {
    float e = __expf(2.0f * x);
    return 1.0f - 2.0f * __builtin_amdgcn_rcpf(e + 1.0f);
}

// ---------------------------------------------------------------- persistent RNN
// 4 WGs x 256 thr; wave w of WG g owns output rows [128g+32w, 128g+32w+32).
// W_hh slice lives in VGPR/AGPR bf16 MFMA A-fragments (2 Mtiles x 16 ksteps).
//
// Sync redesign: NO barriers, NO counters. z is pre-filled with a bf16-NaN
// sentinel; producers store h with fire-and-forget agent-scope 8B atomics,
// consumers load h(t-1) and simply RE-LOAD while any lane still sees the
// sentinel (tanh can never produce NaN, 8B atomics can't tear). The per-step
// critical path collapses from ~4 serialized coherence round trips
// (store-drain + fetch_add + poll + load) to ~1 transit + detect.
__global__ __launch_bounds__(256, 1) void rnn_k(
    const float* __restrict__ Whh,   // [512][512]
    const float* __restrict__ xp,    // [8][2048][512]  (x@W_ih^T + b_ih + b_hh)
    bf16* __restrict__ z)            // [8][2048][512], pre-filled with SENT8
{
    const int g = blockIdx.x;
    const int tid = threadIdx.x;
    const int wave = tid >> 6, lane = tid & 63;
    const int lr = lane >> 4, lc = lane & 15;
    const int rowbase = g * 128 + wave * 32;

    // preload W_hh fragments: A[m=lane&15][k=quad*8+j]   (128 regs)
    bf16x8 a[2][16];
#pragma unroll
    for (int mt = 0; mt < 2; mt++) {
        const long m = rowbase + mt * 16 + lc;
#pragma unroll
        for (int kt = 0; kt < 16; kt++) {
            const float* s = Whh + m * 512 + kt * 32 + lr * 8;
            f32x4 u0 = *(const f32x4*)s;
            f32x4 u1 = *(const f32x4*)(s + 4);
            union { bf16x8 v; bf16 h[8]; } cv;
            cv.h[0] = __float2bfloat16(u0[0]); cv.h[1] = __float2bfloat16(u0[1]);
            cv.h[2] = __float2bfloat16(u0[2]); cv.h[3] = __float2bfloat16(u0[3]);
            cv.h[4] = __float2bfloat16(u1[0]); cv.h[5] = __float2bfloat16(u1[1]);
            cv.h[6] = __float2bfloat16(u1[2]); cv.h[7] = __float2bfloat16(u1[3]);
            a[mt][kt] = cv.v;
        }
    }

    const int b  = lc;              // batch (C-frag col); lanes with b>=8 are spectators
    const int bb = (b < 8) ? b : 0;

    for (int t = 0; t < 2048; t++) {
        // xp prefetch (plain cached loads; written before this kernel)
        f32x4 xv[2];
#pragma unroll
        for (int mt = 0; mt < 2; mt++)
            xv[mt] = *(const f32x4*)(xp + ((long)bb * 2048 + t) * 512 + rowbase + mt * 16 + lr * 4);

        // split-parity accumulators: halves the dependent-MFMA chain depth
        f32x4 acc[2][2] = {};
        if (t > 0) {
            const unsigned long long* hrow =
                (const unsigned long long*)(z + ((long)bb * 2048 + (t - 1)) * 512);
            unsigned long long bl[16][2];
#pragma unroll
            for (int kt = 0; kt < 16; kt++) {
                const unsigned long long* p = hrow + kt * 8 + lr * 2;
                bl[kt][0] = __hip_atomic_load(p,     __ATOMIC_RELAXED, SCOPE_AGENT);
                bl[kt][1] = __hip_atomic_load(p + 1, __ATOMIC_RELAXED, SCOPE_AGENT);
            }
            // value-based sync: retry until no lane sees the sentinel
            long tries = 0;
            for (;;) {
                bool bad = false;
#pragma unroll
                for (int kt = 0; kt < 16; kt++)
                    bad |= (bl[kt][0] == SENT8) || (bl[kt][1] == SENT8);
                if (!__any(bad)) break;
                if (++tries > 2000000L) break;   // no-hang escape (wrong result, no deadlock)
#pragma unroll
                for (int kt = 0; kt < 16; kt++) {
                    const unsigned long long* p = hrow + kt * 8 + lr * 2;
                    bl[kt][0] = __hip_atomic_load(p,     __ATOMIC_RELAXED, SCOPE_AGENT);
                    bl[kt][1] = __hip_atomic_load(p + 1, __ATOMIC_RELAXED, SCOPE_AGENT);
                }
            }
            __builtin_amdgcn_sched_barrier(0);
#pragma unroll
            for (int kt = 0; kt < 16; kt++) {
                union { unsigned long long u[2]; bf16x8 v; } bv;
                bv.u[0] = bl[kt][0]; bv.u[1] = bl[kt][1];
                acc[0][kt & 1] = __builtin_amdgcn_mfma_f32_16x16x32_bf16(a[0][kt], bv.v, acc[0][kt & 1], 0, 0, 0);
                acc[1][kt & 1] = __builtin_amdgcn_mfma_f32_16x16x32_bf16(a[1][kt], bv.v, acc[1][kt & 1], 0, 0, 0);
            }
        }
        // epilogue: h = tanh(acc + xp); publish fire-and-forget (no drain!)
        if (b < 8) {
#pragma unroll
            for (int mt = 0; mt < 2; mt++) {
                union { unsigned long long u; bf16 h[4]; } pk;
#pragma unroll
                for (int i = 0; i < 4; i++)
                    pk.h[i] = __float2bfloat16(fast_tanh(acc[mt][0][i] + acc[mt][1][i] + xv[mt][i]));
                unsigned long long* dst =
                    (unsigned long long*)(z + ((long)b * 2048 + t) * 512 + rowbase + mt * 16 + lr * 4);
                __hip_atomic_store(dst, pk.u, __ATOMIC_RELAXED, SCOPE_AGENT);
            }
        }
        // no __syncthreads: waves free-run, the sentinel check IS the sync
    }
}

// ---------------------------------------------------------------- masked softmax, bf16 in place
// scores fp32 [8][2048][2048] in buf; keep col<row else -1e9; writes bf16 probs
// over the first half of each fp32 row (row pitch stays 2048 fp32 = 4096 bf16).
__global__ __launch_bounds__(256) void softmax_k(float* __restrict__ buf) {
    const long r = blockIdx.x, b = blockIdx.y;
    float* row = buf + (b * 2048 + r) * 2048;
    bf16* out  = (bf16*)row;
    const int tid = threadIdx.x;

    f32x4 u0 = *(const f32x4*)(row + tid * 8);
    f32x4 u1 = *(const f32x4*)(row + tid * 8 + 4);
    float v[8] = {u0[0], u0[1], u0[2], u0[3], u1[0], u1[1], u1[2], u1[3]};
#pragma unroll
    for (int j = 0; j < 8; j++) { int c = tid * 8 + j; if (c >= r) v[j] = -1.0e9f; }

    float mx = v[0];
#pragma unroll
    for (int j = 1; j < 8; j++) mx = fmaxf(mx, v[j]);
#pragma unroll
    for (int o = 32; o > 0; o >>= 1) mx = fmaxf(mx, __shfl_xor(mx, o, 64));
    __shared__ float sm[4], ss[4];
    const int wave = tid >> 6, lane = tid & 63;
    if (!lane) sm[wave] = mx;
    __syncthreads();
    mx = fmaxf(fmaxf(sm[0], sm[1]), fmaxf(sm[2], sm[3]));

    float p[8], s = 0.f;
#pragma unroll
    for (int j = 0; j < 8; j++) { p[j] = expf(v[j] - mx); s += p[j]; }   // r==0 -> all 1 -> uniform
#pragma unroll
    for (int o = 32; o > 0; o >>= 1) s += __shfl_xor(s, o, 64);
    if (!lane) ss[wave] = s;
    __syncthreads();   // also fences all reads before the in-place writes
    s = ss[0] + ss[1] + ss[2] + ss[3];
    const float inv = 1.0f / s;

    union { uint4 u; bf16 h[8]; } o8;
#pragma unroll
    for (int j = 0; j < 8; j++) o8.h[j] = __float2bfloat16(p[j] * inv);
    *(uint4*)(out + tid * 8) = o8.u;
}

// ---------------------------------------------------------------- launch
extern "C" void kernel_launch(void* const* d_in, const int* in_sizes, int n_in,
                              void* d_out, int out_size, void* d_ws, size_t ws_size,
                              hipStream_t stream) {
    const int*   batch = (const int*)  d_in[0];
    const float* emb   = (const float*)d_in[1];
    const float* W_ih  = (const float*)d_in[2];
    const float* b_ih  = (const float*)d_in[3];
    const float* W_hh  = (const float*)d_in[4];
    const float* b_hh  = (const float*)d_in[5];
    const float* W_c   = (const float*)d_in[6];
    const float* b_c   = (const float*)d_in[7];
    const float* W_d   = (const float*)d_in[8];
    const float* b_d   = (const float*)d_in[9];

    // d_out (655 MB) doubles as scratch; lifetimes are disjoint, K6 rewrites all.
    char* ob = (char*)d_out;
    float* scores = (float*)ob;                         // [8][2048][2048] fp32 -> bf16 probs in place
    bf16*  att    = (bf16*)ob;                          // bf16 view, row pitch 4096
    bf16*  emb_bf = (bf16*)(ob + 134217728);            // [10000][512]
    bf16*  wih_bf = (bf16*)(ob + 144457728);            // [512][512]
    bf16*  wc_bf  = (bf16*)(ob + 144982016);            // [512][1024]
    float* xp     = (float*)(ob + 146030592);           // [8][2048][512]; reused as dec fp32
    bf16*  z      = (bf16*)(ob + 179585024);            // [8][2048][512]
    bf16*  attv   = (bf16*)(ob + 196362240);            // [8][2048][512]

    // d_ws: only buffers K6 reads while writing d_out (+ sync state). ~27 MB.
    char* wb = (char*)d_ws;
    unsigned* cnt   = (unsigned*)wb;                    // [2048] (unused by rnn now)
    float* bias_sum = (float*)(wb + 8192);              // [512] = b_ih + b_hh
    bf16*  dec_bf   = (bf16*)(wb + 10240);              // [16384][512]
    bf16*  wd_bf    = (bf16*)(wb + 16787456);           // [10000][512]

    prep_k<<<8, 256, 0, stream>>>(b_ih, b_hh, bias_sum, cnt);
    f2b_k<<<1024, 256, 0, stream>>>(emb, emb_bf, 5120000);
    f2b_k<<<256, 256, 0, stream>>>(W_ih, wih_bf, 262144);
    f2b_k<<<256, 256, 0, stream>>>(W_c, wc_bf, 524288);
    f2b_k<<<1024, 256, 0, stream>>>(W_d, wd_bf, 5120000);
    // sentinel-fill z: 8*2048*512*2B / 8 = 2,097,152 ULLs
    fill_k<<<2048, 256, 0, stream>>>((unsigned long long*)z, 2097152);

    // K1: xp = emb[batch] @ W_ih^T + (b_ih + b_hh)
    gemm_k<true, false, false, true, true><<<dim3(4, 128, 1), 256, 0, stream>>>(
        emb_bf, 512, 0, batch, wih_bf, 512, 0, bias_sum, nullptr, 0,
        xp, 512, 0, 16384, 512, 512);

    // RNN scan -> z (bf16)
    rnn_k<<<4, 256, 0, stream>>>(W_hh, xp, z);

    // K2: scores[b] = z[b] @ z[b]^T   (fp32 into d_out)
    gemm_k<true, false, false, false, false><<<dim3(16, 16, 8), 256, 0, stream>>>(
        z, 512, (long)2048 * 512, nullptr, z, 512, (long)2048 * 512, nullptr, nullptr, 0,
        scores, 2048, (long)2048 * 2048, 2048, 2048, 512);

    // K3: causal masked softmax, bf16 probs in place
    softmax_k<<<dim3(2048, 8), 256, 0, stream>>>(scores);

    // K4: att_vec[b] = att[b] @ z[b]
    gemm_k<false, true, false, false, false><<<dim3(4, 16, 8), 256, 0, stream>>>(
        att, 4096, (long)2048 * 4096, nullptr, z, 512, (long)2048 * 512, nullptr, nullptr, 0,
        attv, 512, (long)2048 * 512, 2048, 512, 2048);

    // K5a: dec_f32 = att_vec @ W_c[:, :512]^T + b_c   (into xp buffer)
    gemm_k<true, false, false, true, false><<<dim3(4, 128, 1), 256, 0, stream>>>(
        attv, 512, 0, nullptr, wc_bf, 1024, 0, b_c, nullptr, 0,
        xp, 512, 0, 16384, 512, 512);
    // K5b: dec_bf16 = dec_f32 + z @ W_c[:, 512:]^T
    gemm_k<true, true, true, false, false><<<dim3(4, 128, 1), 256, 0, stream>>>(
        z, 512, 0, nullptr, wc_bf + 512, 1024, 0, nullptr, xp, 512,
        dec_bf, 512, 0, 16384, 512, 512);

    // K6: logits = dec @ W_d^T + b_d  -> d_out fp32 (rewrites everything)
    gemm_k<true, false, false, true, false><<<dim3(79, 128, 1), 256, 0, stream>>>(
        dec_bf, 512, 0, nullptr, wd_bf, 512, 0, b_d, nullptr, 0,
        (float*)d_out, 10000, 0, 16384, 10000, 512);
}

// Round 3
// 6176.759 us; speedup vs baseline: 2.0114x; 2.0114x over previous
//
#include <hip/hip_runtime.h>
#include <hip/hip_bf16.h>

typedef __hip_bfloat16 bf16;
typedef __attribute__((ext_vector_type(8))) short bf16x8;
typedef __attribute__((ext_vector_type(4))) float f32x4;

// ---------------------------------------------------------------- prep
__global__ void prep_k(const float* __restrict__ b_ih, const float* __restrict__ b_hh,
                       float* __restrict__ bias_sum) {
    int i = blockIdx.x * 256 + threadIdx.x;
    if (i < 512) bias_sum[i] = b_ih[i] + b_hh[i];
}

__global__ void f2b_k(const float* __restrict__ in, bf16* __restrict__ out, long n) {
    long i = (long)blockIdx.x * blockDim.x + threadIdx.x;
    long stride = (long)gridDim.x * blockDim.x;
    for (; i < n; i += stride) out[i] = __float2bfloat16(in[i]);
}

// ---------------------------------------------------------------- generic bf16 MFMA GEMM
// C[m,n] = sum_k A(m,k)*B(k,n)  (+ Cin, + bias[n])
// A(m,k) = A[(gather?gidx[m]:m)*lda + k]          (row-major over k)
// BT=true : B(k,n) = B[n*ldb + k]  (B stored [N][K], i.e. B^T row-major)
// BT=false: B(k,n) = B[k*ldb + n]  (B stored [K][N] row-major)
template<bool BT, bool OUT_BF16, bool ACCUM, bool BIAS, bool GATHER>
__global__ __launch_bounds__(256) void gemm_k(
    const bf16* __restrict__ A, long lda, long a_bs,
    const int* __restrict__ gidx,
    const bf16* __restrict__ B, long ldb, long b_bs,
    const float* __restrict__ bias,
    const float* __restrict__ Cin, long ldcin,
    void* __restrict__ Cout, long ldc, long c_bs,
    int M, int N, int K)
{
    constexpr int BM = 128, BN = 128, BK = 32, PAD = 8;
    __shared__ bf16 As[BM][BK + PAD];   // [m][k]
    __shared__ bf16 Bs[BN][BK + PAD];   // [n][k]

    const int tid  = threadIdx.x;
    const int m0   = blockIdx.y * BM, n0 = blockIdx.x * BN;
    const long bat = blockIdx.z;
    const bf16* Ab = A + bat * a_bs;
    const bf16* Bb = B + bat * b_bs;
    const int wave = tid >> 6, lane = tid & 63;
    const int wm = (wave >> 1) * 64, wn = (wave & 1) * 64;
    const int lr = lane >> 4, lc = lane & 15;

    f32x4 acc[4][4] = {};

    for (int k0 = 0; k0 < K; k0 += BK) {
        // stage A tile: 128x32 bf16, 16B chunks
#pragma unroll
        for (int it = 0; it < 2; it++) {
            int c = tid + it * 256;
            int m = c >> 2, kc = (c & 3) * 8;
            long arow;
            if (GATHER) arow = (long)gidx[m0 + m];
            else        arow = (long)(m0 + m);
            *(uint4*)&As[m][kc] = *(const uint4*)(Ab + arow * lda + (k0 + kc));
        }
        if (BT) {
#pragma unroll
            for (int it = 0; it < 2; it++) {
                int c = tid + it * 256;
                int n = c >> 2, kc = (c & 3) * 8;
                int gn = n0 + n; if (gn >= N) gn = N - 1;   // clamp (K6: N=10000)
                *(uint4*)&Bs[n][kc] = *(const uint4*)(Bb + (long)gn * ldb + (k0 + kc));
            }
        } else {
            // B row-major [K][N]: read 8 along n, transpose into Bs
#pragma unroll
            for (int it = 0; it < 2; it++) {
                int c = tid + it * 256;
                int k = c >> 4, nc = (c & 15) * 8;
                union { uint4 u; bf16 h[8]; } uu;
                uu.u = *(const uint4*)(Bb + (long)(k0 + k) * ldb + (n0 + nc));
#pragma unroll
                for (int j = 0; j < 8; j++) Bs[nc + j][k] = uu.h[j];
            }
        }
        __syncthreads();

        bf16x8 af[4], bfr[4];
#pragma unroll
        for (int t = 0; t < 4; t++) {
            af[t]  = *(const bf16x8*)&As[wm + t * 16 + lc][lr * 8];
            bfr[t] = *(const bf16x8*)&Bs[wn + t * 16 + lc][lr * 8];
        }
#pragma unroll
        for (int mt = 0; mt < 4; mt++)
#pragma unroll
            for (int nt = 0; nt < 4; nt++)
                acc[mt][nt] = __builtin_amdgcn_mfma_f32_16x16x32_bf16(af[mt], bfr[nt], acc[mt][nt], 0, 0, 0);
        __syncthreads();
    }

    const long cb = bat * c_bs;
#pragma unroll
    for (int mt = 0; mt < 4; mt++)
#pragma unroll
        for (int nt = 0; nt < 4; nt++)
#pragma unroll
            for (int i = 0; i < 4; i++) {
                int r  = m0 + wm + mt * 16 + lr * 4 + i;   // row = quad*4+reg (m89)
                int cc = n0 + wn + nt * 16 + lc;           // col = lane&15
                if (r < M && cc < N) {
                    float v = acc[mt][nt][i];
                    if (ACCUM) v += Cin[(long)r * ldcin + cc];
                    if (BIAS)  v += bias[cc];
                    if (OUT_BF16) ((bf16*)Cout)[cb + (long)r * ldc + cc] = __float2bfloat16(v);
                    else          ((float*)Cout)[cb + (long)r * ldc + cc] = v;
                }
            }
}

// fast tanh: 1 - 2/(e^{2x}+1). Saturates exactly to +-1 (e^{2x}=inf -> 1;
// e^{2x}=0 -> -1). Error ~1e-6 relative, far below bf16 rounding.
__device__ __forceinline__ float fast_tanh(float x) {
    float e = __expf(2.0f * x);
    return 1.0f - 2.0f * __builtin_amdgcn_rcpf(e + 1.0f);
}

// ---------------------------------------------------------------- single-CU persistent RNN
// ONE workgroup, 1024 threads = 16 waves = 4 waves/SIMD on ONE CU.
// Wave w owns output rows [32w, 32w+32) (2 Mtiles of 16).
// W_hh: k[0:384) as VGPR A-fragments (a[2][12], 96 regs/thread);
//       k[384:512) in LDS (512 x 136-pitch bf16, 139 KB).
// h exchange entirely through LDS ping-pong (hl[2][8][520]) — no cross-XCD
// coherence traffic at all.  One __syncthreads per step: the barrier globally
// separates steps, and step t writes hl[t&1] while reading hl[(t-1)&1].
// z published with PLAIN global stores, deferred by one step so the barrier's
// vmcnt(0) drain never waits on a just-issued store ack; visibility for the
// following GEMM is guaranteed by the kernel boundary.
__global__ __launch_bounds__(1024) void rnn_k(
    const float* __restrict__ Whh,   // [512][512] fp32
    const float* __restrict__ xp,    // [8][2048][512]  (x@W_ih^T + b_ih + b_hh)
    bf16* __restrict__ z)            // [8][2048][512]
{
    __shared__ bf16 wl[512 * 136];       // W rows x k[384:512), pitch 136 (16B-aligned rows, 2-way banks)
    __shared__ bf16 hl[2][8][520];       // ping-pong h: [buf][batch][hidden], pitch 520

    const int tid  = threadIdx.x;
    const int wave = tid >> 6, lane = tid & 63;
    const int lr = lane >> 4, lc = lane & 15;
    const int rowbase = wave * 32;
    const int b = lc, bb = lc & 7;       // batch col; lanes 8-15 duplicate 0-7 (broadcast reads, no writes)

    // ---- stage W k-tail [384:512) into LDS as bf16 (one-time)
#pragma unroll
    for (int it = 0; it < 8; it++) {
        int e = (it * 1024 + tid) * 8;            // 512*128/8 = 8192 chunks, exact
        int row = e >> 7, kc = e & 127;
        const float* s = Whh + (long)row * 512 + 384 + kc;
        f32x4 u0 = *(const f32x4*)s, u1 = *(const f32x4*)(s + 4);
        union { bf16x8 v; bf16 h[8]; } cv;
        cv.h[0] = __float2bfloat16(u0[0]); cv.h[1] = __float2bfloat16(u0[1]);
        cv.h[2] = __float2bfloat16(u0[2]); cv.h[3] = __float2bfloat16(u0[3]);
        cv.h[4] = __float2bfloat16(u1[0]); cv.h[5] = __float2bfloat16(u1[1]);
        cv.h[6] = __float2bfloat16(u1[2]); cv.h[7] = __float2bfloat16(u1[3]);
        *(bf16x8*)&wl[row * 136 + kc] = cv.v;
    }

    // ---- W k[0:384) as VGPR MFMA A-fragments: A[m=lane&15][k=quad*8+j]
    bf16x8 a[2][12];
#pragma unroll
    for (int mt = 0; mt < 2; mt++) {
        const long m = rowbase + mt * 16 + lc;
#pragma unroll
        for (int kt = 0; kt < 12; kt++) {
            const float* s = Whh + m * 512 + kt * 32 + lr * 8;
            f32x4 u0 = *(const f32x4*)s, u1 = *(const f32x4*)(s + 4);
            union { bf16x8 v; bf16 h[8]; } cv;
            cv.h[0] = __float2bfloat16(u0[0]); cv.h[1] = __float2bfloat16(u0[1]);
            cv.h[2] = __float2bfloat16(u0[2]); cv.h[3] = __float2bfloat16(u0[3]);
            cv.h[4] = __float2bfloat16(u1[0]); cv.h[5] = __float2bfloat16(u1[1]);
            cv.h[6] = __float2bfloat16(u1[2]); cv.h[7] = __float2bfloat16(u1[3]);
            a[mt][kt] = cv.v;
        }
    }

    const float* xpp = xp + (long)bb * (2048L * 512) + rowbase + lr * 4;
    bf16*       zp  = z  + (long)b  * (2048L * 512) + rowbase + lr * 4;

    unsigned long long zs0 = 0, zs1 = 0;

    __syncthreads();   // W_lds staged

    for (int t = 0; t < 2048; t++) {
        // deferred z store of step t-1 (plain, fire & forget; acked well before next barrier)
        if (t > 0 && b < 8) {
            *(unsigned long long*)(zp + (long)(t - 1) * 512)      = zs0;
            *(unsigned long long*)(zp + (long)(t - 1) * 512 + 16) = zs1;
        }
        // xp for this step: issued before MFMA phase, consumed in epilogue
        f32x4 xv0 = *(const f32x4*)(xpp + (long)t * 512);
        f32x4 xv1 = *(const f32x4*)(xpp + (long)t * 512 + 16);

        f32x4 acc0 = {0.f, 0.f, 0.f, 0.f}, acc1 = {0.f, 0.f, 0.f, 0.f};
        if (t > 0) {
            const bf16* hb = &hl[(t - 1) & 1][bb][0];
#pragma unroll
            for (int kt = 0; kt < 12; kt++) {
                bf16x8 bv = *(const bf16x8*)&hb[kt * 32 + lr * 8];
                acc0 = __builtin_amdgcn_mfma_f32_16x16x32_bf16(a[0][kt], bv, acc0, 0, 0, 0);
                acc1 = __builtin_amdgcn_mfma_f32_16x16x32_bf16(a[1][kt], bv, acc1, 0, 0, 0);
            }
#pragma unroll
            for (int kt = 12; kt < 16; kt++) {
                bf16x8 bv = *(const bf16x8*)&hb[kt * 32 + lr * 8];
                bf16x8 a0 = *(const bf16x8*)&wl[(rowbase + lc) * 136 + (kt - 12) * 32 + lr * 8];
                bf16x8 a1 = *(const bf16x8*)&wl[(rowbase + 16 + lc) * 136 + (kt - 12) * 32 + lr * 8];
                acc0 = __builtin_amdgcn_mfma_f32_16x16x32_bf16(a0, bv, acc0, 0, 0, 0);
                acc1 = __builtin_amdgcn_mfma_f32_16x16x32_bf16(a1, bv, acc1, 0, 0, 0);
            }
        }
        // epilogue: h = tanh(acc + xp)
        union { unsigned long long u; bf16 h[4]; } p0, p1;
#pragma unroll
        for (int i = 0; i < 4; i++) {
            p0.h[i] = __float2bfloat16(fast_tanh(acc0[i] + xv0[i]));
            p1.h[i] = __float2bfloat16(fast_tanh(acc1[i] + xv1[i]));
        }
        zs0 = p0.u; zs1 = p1.u;
        if (b < 8) {
            *(unsigned long long*)&hl[t & 1][b][rowbase + lr * 4]      = p0.u;
            *(unsigned long long*)&hl[t & 1][b][rowbase + 16 + lr * 4] = p1.u;
        }
        __syncthreads();   // lgkmcnt(0): h(t) visible; separates step t from t+1
    }
    if (b < 8) {
        *(unsigned long long*)(zp + 2047L * 512)      = zs0;
        *(unsigned long long*)(zp + 2047L * 512 + 16) = zs1;
    }
}

// ---------------------------------------------------------------- masked softmax, bf16 in place
// scores fp32 [8][2048][2048] in buf; keep col<row else -1e9; writes bf16 probs
// over the first half of each fp32 row (row pitch stays 2048 fp32 = 4096 bf16).
__global__ __launch_bounds__(256) void softmax_k(float* __restrict__ buf) {
    const long r = blockIdx.x, b = blockIdx.y;
    float* row = buf + (b * 2048 + r) * 2048;
    bf16* out  = (bf16*)row;
    const int tid = threadIdx.x;

    f32x4 u0 = *(const f32x4*)(row + tid * 8);
    f32x4 u1 = *(const f32x4*)(row + tid * 8 + 4);
    float v[8] = {u0[0], u0[1], u0[2], u0[3], u1[0], u1[1], u1[2], u1[3]};
#pragma unroll
    for (int j = 0; j < 8; j++) { int c = tid * 8 + j; if (c >= r) v[j] = -1.0e9f; }

    float mx = v[0];
#pragma unroll
    for (int j = 1; j < 8; j++) mx = fmaxf(mx, v[j]);
#pragma unroll
    for (int o = 32; o > 0; o >>= 1) mx = fmaxf(mx, __shfl_xor(mx, o, 64));
    __shared__ float sm[4], ss[4];
    const int wave = tid >> 6, lane = tid & 63;
    if (!lane) sm[wave] = mx;
    __syncthreads();
    mx = fmaxf(fmaxf(sm[0], sm[1]), fmaxf(sm[2], sm[3]));

    float p[8], s = 0.f;
#pragma unroll
    for (int j = 0; j < 8; j++) { p[j] = expf(v[j] - mx); s += p[j]; }   // r==0 -> all 1 -> uniform
#pragma unroll
    for (int o = 32; o > 0; o >>= 1) s += __shfl_xor(s, o, 64);
    if (!lane) ss[wave] = s;
    __syncthreads();   // also fences all reads before the in-place writes
    s = ss[0] + ss[1] + ss[2] + ss[3];
    const float inv = 1.0f / s;

    union { uint4 u; bf16 h[8]; } o8;
#pragma unroll
    for (int j = 0; j < 8; j++) o8.h[j] = __float2bfloat16(p[j] * inv);
    *(uint4*)(out + tid * 8) = o8.u;
}

// ---------------------------------------------------------------- launch
extern "C" void kernel_launch(void* const* d_in, const int* in_sizes, int n_in,
                              void* d_out, int out_size, void* d_ws, size_t ws_size,
                              hipStream_t stream) {
    const int*   batch = (const int*)  d_in[0];
    const float* emb   = (const float*)d_in[1];
    const float* W_ih  = (const float*)d_in[2];
    const float* b_ih  = (const float*)d_in[3];
    const float* W_hh  = (const float*)d_in[4];
    const float* b_hh  = (const float*)d_in[5];
    const float* W_c   = (const float*)d_in[6];
    const float* b_c   = (const float*)d_in[7];
    const float* W_d   = (const float*)d_in[8];
    const float* b_d   = (const float*)d_in[9];

    // d_out (655 MB) doubles as scratch; lifetimes are disjoint, K6 rewrites all.
    char* ob = (char*)d_out;
    float* scores = (float*)ob;                         // [8][2048][2048] fp32 -> bf16 probs in place
    bf16*  att    = (bf16*)ob;                          // bf16 view, row pitch 4096
    bf16*  emb_bf = (bf16*)(ob + 134217728);            // [10000][512]
    bf16*  wih_bf = (bf16*)(ob + 144457728);            // [512][512]
    bf16*  wc_bf  = (bf16*)(ob + 144982016);            // [512][1024]
    float* xp     = (float*)(ob + 146030592);           // [8][2048][512]; reused as dec fp32
    bf16*  z      = (bf16*)(ob + 179585024);            // [8][2048][512]
    bf16*  attv   = (bf16*)(ob + 196362240);            // [8][2048][512]

    // d_ws: only buffers K6 reads while writing d_out (+ misc). ~27 MB.
    char* wb = (char*)d_ws;
    float* bias_sum = (float*)(wb + 8192);              // [512] = b_ih + b_hh
    bf16*  dec_bf   = (bf16*)(wb + 10240);              // [16384][512]
    bf16*  wd_bf    = (bf16*)(wb + 16787456);           // [10000][512]

    prep_k<<<2, 256, 0, stream>>>(b_ih, b_hh, bias_sum);
    f2b_k<<<1024, 256, 0, stream>>>(emb, emb_bf, 5120000);
    f2b_k<<<256, 256, 0, stream>>>(W_ih, wih_bf, 262144);
    f2b_k<<<256, 256, 0, stream>>>(W_c, wc_bf, 524288);
    f2b_k<<<1024, 256, 0, stream>>>(W_d, wd_bf, 5120000);

    // K1: xp = emb[batch] @ W_ih^T + (b_ih + b_hh)
    gemm_k<true, false, false, true, true><<<dim3(4, 128, 1), 256, 0, stream>>>(
        emb_bf, 512, 0, batch, wih_bf, 512, 0, bias_sum, nullptr, 0,
        xp, 512, 0, 16384, 512, 512);

    // RNN scan -> z (bf16), single CU, LDS-everything
    rnn_k<<<1, 1024, 0, stream>>>(W_hh, xp, z);

    // K2: scores[b] = z[b] @ z[b]^T   (fp32 into d_out)
    gemm_k<true, false, false, false, false><<<dim3(16, 16, 8), 256, 0, stream>>>(
        z, 512, (long)2048 * 512, nullptr, z, 512, (long)2048 * 512, nullptr, nullptr, 0,
        scores, 2048, (long)2048 * 2048, 2048, 2048, 512);

    // K3: causal masked softmax, bf16 probs in place
    softmax_k<<<dim3(2048, 8), 256, 0, stream>>>(scores);

    // K4: att_vec[b] = att[b] @ z[b]
    gemm_k<false, true, false, false, false><<<dim3(4, 16, 8), 256, 0, stream>>>(
        att, 4096, (long)2048 * 4096, nullptr, z, 512, (long)2048 * 512, nullptr, nullptr, 0,
        attv, 512, (long)2048 * 512, 2048, 512, 2048);

    // K5a: dec_f32 = att_vec @ W_c[:, :512]^T + b_c   (into xp buffer)
    gemm_k<true, false, false, true, false><<<dim3(4, 128, 1), 256, 0, stream>>>(
        attv, 512, 0, nullptr, wc_bf, 1024, 0, b_c, nullptr, 0,
        xp, 512, 0, 16384, 512, 512);
    // K5b: dec_bf16 = dec_f32 + z @ W_c[:, 512:]^T
    gemm_k<true, true, true, false, false><<<dim3(4, 128, 1), 256, 0, stream>>>(
        z, 512, 0, nullptr, wc_bf + 512, 1024, 0, nullptr, xp, 512,
        dec_bf, 512, 0, 16384, 512, 512);

    // K6: logits = dec @ W_d^T + b_d  -> d_out fp32 (rewrites everything)
    gemm_k<true, false, false, true, false><<<dim3(79, 128, 1), 256, 0, stream>>>(
        dec_bf, 512, 0, nullptr, wd_bf, 512, 0, b_d, nullptr, 0,
        (float*)d_out, 10000, 0, 16384, 10000, 512);
}